// Round 12
// baseline (124.650 us; speedup 1.0000x reference)
//
#include <hip/hip_runtime.h>
#include <stdint.h>

// DBMLLoss on MI355X — round 12 (= round 10/11 resubmitted; two infra timeouts, never ran).
// feats: [4096,512] f32 (L2-normalized rows), labels: [4096] i32, out: scalar f32.
// Path A: convert (LDS-tiled transpose, coalesced both sides) -> phase1 (GEMM +
//   pass-1 fold + bf16 sim write; UNCHANGED from round 7/9, 46.2us verified) ->
//   pass2 (one wave per row, no LDS/sync) -> sum.
// Round-9 lesson: phase1 is 46us of a 122us total; the other ~76us hides in
// convert's uncoalesced transpose reads and pass2's per-block fixed costs.

#define Bn 4096
#define Dk 512
#define NCHUNK 16         // col chunks; grid = 32 x 16 = 512 blocks
#define CWIDTH 256        // cols per chunk
#define BM 128            // rows per block
#define TBN 128           // cols per tile step
#define BK 64             // K step
#define NSTEP 16          // (CWIDTH/TBN) * (Dk/BK)
#define ONE_EPS 0.99999f  // 1 - 1e-5

typedef short bf16x8 __attribute__((ext_vector_type(8)));
typedef unsigned short u16x4 __attribute__((ext_vector_type(4)));
typedef float f32x4 __attribute__((ext_vector_type(4)));

__device__ __forceinline__ unsigned short f2bf(float x) {
  unsigned int u = __float_as_uint(x);
  u += 0x7fffu + ((u >> 16) & 1u);   // RNE
  return (unsigned short)(u >> 16);
}

// featT layout: [kb 0..63][row 0..4095][8 bf16]  (kb = k/8).
// LDS-tiled transpose: reads 64B/thread contiguous, writes 32B/thread contiguous.
__global__ __launch_bounds__(256) void convert_kernel(const float* __restrict__ feats,
                                                      unsigned short* __restrict__ featT) {
  __shared__ unsigned short tile[8][64][8];  // [kbl][rowl][e] = 8 KB
  const int t = threadIdx.x;
  const int r0 = (blockIdx.x & 63) * 64;    // row tile
  const int kb0 = (blockIdx.x >> 6) * 8;    // kb tile
  {
    const int rowl = t >> 2;                // 4 threads per row
    const int c0 = (t & 3) * 16;            // 16 consecutive floats each
    const float* src = feats + (size_t)(r0 + rowl) * Dk + kb0 * 8 + c0;
    f32x4 f[4];
#pragma unroll
    for (int i = 0; i < 4; ++i) f[i] = ((const f32x4*)src)[i];
    union { unsigned short u[16]; bf16x8 v[2]; } o;
#pragma unroll
    for (int j = 0; j < 16; ++j) o.u[j] = f2bf(f[j >> 2][j & 3]);
    const int kbl = (t & 3) * 2;
    *(bf16x8*)&tile[kbl][rowl][0] = o.v[0];
    *(bf16x8*)&tile[kbl + 1][rowl][0] = o.v[1];
  }
  __syncthreads();
  {
    const int kbl = t >> 5;                 // 32 threads per kb
    const int rowl = (t & 31) * 2;          // 2 rows each -> 32B contiguous
    bf16x8 a = *(const bf16x8*)&tile[kbl][rowl][0];
    bf16x8 b = *(const bf16x8*)&tile[kbl][rowl + 1][0];
    unsigned short* dst = featT + (size_t)(kb0 + kbl) * Bn * 8 + (size_t)(r0 + rowl) * 8;
    *(bf16x8*)dst = a;
    *(bf16x8*)(dst + 8) = b;
  }
}

__device__ __forceinline__ void gload16(const unsigned short* g, short* l) {
  __builtin_amdgcn_global_load_lds((const __attribute__((address_space(1))) unsigned int*)g,
                                   (__attribute__((address_space(3))) unsigned int*)l,
                                   16, 0, 0);
}

// PHASE 1 partials (5): sum, sumsq, max_neg, min_pos, pos_cnt  (+ optional sim write)
// PHASE 2 partials (6): fallback path only
template <int PHASE, bool WSIM>
__global__ __launch_bounds__(512, 2) void phase_kernel(const unsigned short* __restrict__ featT,
                                                       const int* __restrict__ labels,
                                                       const float* __restrict__ rs,
                                                       float* __restrict__ part,
                                                       unsigned short* __restrict__ simb) {
  // double-buffered LDS tiles, k-outer: [kb 0..7][r 0..127][8 bf16]
  __shared__ short As[2][8192];
  __shared__ short Bs[2][8192];
  __shared__ int rl[BM];
  __shared__ int cl[CWIDTH];

  const int tid = threadIdx.x;
  const int wid = tid >> 6;
  const int lane = tid & 63;
  const int WR = wid & 3;    // 4 row groups of 32
  const int WC = wid >> 2;   // 2 col groups of 64
  const int l15 = lane & 15;
  const int l4 = lane >> 4;
  const int row0 = blockIdx.x * BM;
  const int chunk0 = blockIdx.y * CWIDTH;

  if (tid < BM) rl[tid] = labels[row0 + tid];
  if (tid < CWIDTH) cl[tid] = labels[chunk0 + tid];

  int rlab[2][4], rowl[2][4];
  float thrp[2][4], thrn[2][4];
#pragma unroll
  for (int m = 0; m < 2; ++m)
#pragma unroll
    for (int r = 0; r < 4; ++r) {
      int lr = WR * 32 + m * 16 + l4 * 4 + r;  // tile-local row (C/D: row=(l>>4)*4+reg)
      rowl[m][r] = lr;
      rlab[m][r] = 0;
      if constexpr (PHASE == 2) {
        thrp[m][r] = rs[2 * Bn + row0 + lr];  // max_neg
        thrn[m][r] = rs[3 * Bn + row0 + lr];  // min_pos
      }
    }

  float s0[2][4], s1[2][4], s2[2][4], s3[2][4], s4[2][4], s5[2][4];
#pragma unroll
  for (int m = 0; m < 2; ++m)
#pragma unroll
    for (int r = 0; r < 4; ++r) {
      s0[m][r] = 0.f; s1[m][r] = 0.f;
      s2[m][r] = (PHASE == 1) ? -__builtin_inff() : 0.f;
      s3[m][r] = (PHASE == 1) ? __builtin_inff() : 0.f;
      s4[m][r] = 0.f; s5[m][r] = 0.f;
    }

  // stage step s: A rows panel + B cols panel for (ct = s>>3, kt = s&7) into buf s&1
  auto stage = [&](int s) {
    const int ct = s >> 3, kt = s & 7, bb = s & 1;
    const int cbase = chunk0 + ct * TBN;
#pragma unroll
    for (int i = 0; i < 2; ++i) {
      const int q = tid + i * 512;
      const int r = q & 127;
      const int kb = q >> 7;
      const int ko = (kt * 8 + kb) * (Bn * 8);
      gload16(featT + ko + (row0 + r) * 8, &As[bb][q * 8]);
      gload16(featT + ko + (cbase + r) * 8, &Bs[bb][q * 8]);
    }
  };

  stage(0);

  for (int ct = 0; ct < CWIDTH / TBN; ++ct) {
    const int col0 = chunk0 + ct * TBN;
    f32x4 acc[2][4];
#pragma unroll
    for (int m = 0; m < 2; ++m)
#pragma unroll
      for (int n = 0; n < 4; ++n) acc[m][n] = (f32x4){0.f, 0.f, 0.f, 0.f};

    for (int kt = 0; kt < Dk / BK; ++kt) {
      const int s = ct * 8 + kt;
      __syncthreads();  // drains stage(s) (issued a full compute phase ago) + publishes
      if (s + 1 < NSTEP) stage(s + 1);
      if (s == 0) {  // labels now visible
#pragma unroll
        for (int m = 0; m < 2; ++m)
#pragma unroll
          for (int r = 0; r < 4; ++r) rlab[m][r] = rl[rowl[m][r]];
      }
      const int bb = s & 1;
#pragma unroll
      for (int ks = 0; ks < 2; ++ks) {
        const int kb = ks * 4 + l4;
        bf16x8 af[2], bf[4];
#pragma unroll
        for (int m = 0; m < 2; ++m)
          af[m] = *(const bf16x8*)&As[bb][(kb * 128 + WR * 32 + m * 16 + l15) * 8];
#pragma unroll
        for (int n = 0; n < 4; ++n)
          bf[n] = *(const bf16x8*)&Bs[bb][(kb * 128 + WC * 64 + n * 16 + l15) * 8];
#pragma unroll
        for (int m = 0; m < 2; ++m)
#pragma unroll
          for (int n = 0; n < 4; ++n)
            acc[m][n] = __builtin_amdgcn_mfma_f32_16x16x32_bf16(af[m], bf[n], acc[m][n], 0, 0, 0);
      }
    }

    // ---- fold this 128x128 tile into per-lane row stats (+ optional sim write) ----
    const bool diag = (col0 == row0);
#pragma unroll
    for (int n = 0; n < 4; ++n) {
      const int lcolt = WC * 64 + n * 16 + l15;            // tile-local col
      const int clab = cl[ct * TBN + lcolt];
#pragma unroll
      for (int m = 0; m < 2; ++m) {
        float tv[4];
#pragma unroll
        for (int r = 0; r < 4; ++r) {
          float s = acc[m][n][r];
          if (diag && (lcolt == rowl[m][r])) s = 1.0f;  // exact self-sim
          tv[r] = s;
        }
        if constexpr (WSIM) {
          u16x4 w;
#pragma unroll
          for (int r = 0; r < 4; ++r) w[r] = f2bf(tv[r]);
          // simb[c][r]: by symmetry this is sim row c. 4 consecutive rows -> 8B store.
          *(u16x4*)(simb + (size_t)(col0 + lcolt) * Bn +
                    (row0 + WR * 32 + m * 16 + l4 * 4)) = w;
        }
#pragma unroll
        for (int r = 0; r < 4; ++r) {
          float s = tv[r];
          bool same = (rlab[m][r] == clab);
          if constexpr (PHASE == 1) {
            s0[m][r] += s;
            s1[m][r] += s * s;
            if (!same) s2[m][r] = fmaxf(s2[m][r], s);
            else if (s < ONE_EPS) { s3[m][r] = fminf(s3[m][r], s); s4[m][r] += 1.0f; }
          } else {
            bool psel = same && (s < ONE_EPS) && (s - 0.1f < thrp[m][r]);
            bool nsel = (!same) && (s + 0.1f > thrn[m][r]);
            if (psel) { s0[m][r] += 1.0f; s4[m][r] += __expf(2.0f - 2.0f * s); }
            if (nsel) { s1[m][r] += 1.0f; s5[m][r] += __expf(2.0f * s - 1.2f); }
            if (psel || nsel) { s2[m][r] += s; s3[m][r] += s * s; }
          }
        }
      }
    }
  }

  // butterfly across the 16 lanes holding different cols of the same rows
#pragma unroll
  for (int d = 1; d < 16; d <<= 1) {
#pragma unroll
    for (int m = 0; m < 2; ++m)
#pragma unroll
      for (int r = 0; r < 4; ++r) {
        s0[m][r] += __shfl_xor(s0[m][r], d);
        s1[m][r] += __shfl_xor(s1[m][r], d);
        if constexpr (PHASE == 1) {
          s2[m][r] = fmaxf(s2[m][r], __shfl_xor(s2[m][r], d));
          s3[m][r] = fminf(s3[m][r], __shfl_xor(s3[m][r], d));
          s4[m][r] += __shfl_xor(s4[m][r], d);
        } else {
          s2[m][r] += __shfl_xor(s2[m][r], d);
          s3[m][r] += __shfl_xor(s3[m][r], d);
          s4[m][r] += __shfl_xor(s4[m][r], d);
          s5[m][r] += __shfl_xor(s5[m][r], d);
        }
      }
  }

  // ---- merge the two WC halves in LDS, then one write per row per block ----
  __syncthreads();  // all compute done; reuse As as float scratch
  float* mbuf = (float*)&As[0][0];  // BM*6 floats = 3 KB
  if (WC == 1 && l15 == 0) {
#pragma unroll
    for (int m = 0; m < 2; ++m)
#pragma unroll
      for (int r = 0; r < 4; ++r) {
        int lr = rowl[m][r];
        mbuf[lr * 6 + 0] = s0[m][r];
        mbuf[lr * 6 + 1] = s1[m][r];
        mbuf[lr * 6 + 2] = s2[m][r];
        mbuf[lr * 6 + 3] = s3[m][r];
        mbuf[lr * 6 + 4] = s4[m][r];
        mbuf[lr * 6 + 5] = s5[m][r];
      }
  }
  __syncthreads();
  if (WC == 0 && l15 == 0) {
    const int slot = blockIdx.y;  // 16 slots per row
#pragma unroll
    for (int m = 0; m < 2; ++m)
#pragma unroll
      for (int r = 0; r < 4; ++r) {
        int lr = rowl[m][r];
        int rowg = row0 + lr;
        const float* p = &mbuf[lr * 6];
        float t0 = s0[m][r] + p[0];
        float t1 = s1[m][r] + p[1];
        float t2, t3;
        if constexpr (PHASE == 1) {
          t2 = fmaxf(s2[m][r], p[2]);
          t3 = fminf(s3[m][r], p[3]);
        } else {
          t2 = s2[m][r] + p[2];
          t3 = s3[m][r] + p[3];
        }
        float t4 = s4[m][r] + p[4];
        part[(size_t)(0 * Bn + rowg) * 16 + slot] = t0;
        part[(size_t)(1 * Bn + rowg) * 16 + slot] = t1;
        part[(size_t)(2 * Bn + rowg) * 16 + slot] = t2;
        part[(size_t)(3 * Bn + rowg) * 16 + slot] = t3;
        part[(size_t)(4 * Bn + rowg) * 16 + slot] = t4;
        if constexpr (PHASE == 2)
          part[(size_t)(5 * Bn + rowg) * 16 + slot] = s5[m][r] + p[5];
      }
  }
}

// ---- Path A pass 2: ONE WAVE per row (64-thread blocks, no LDS, no sync) ----
__global__ __launch_bounds__(64) void pass2_kernel(const unsigned short* __restrict__ simb,
                                                   const int* __restrict__ labels,
                                                   const float* __restrict__ p1,
                                                   float* __restrict__ bres) {
  const int lane = threadIdx.x;
  const int row = blockIdx.x;
  const int rlab = labels[row];

  // pass-1 slot reduce (16 slots; lanes duplicate in 16-groups)
  const int sl = lane & 15;
  float ssum = p1[(size_t)(0 * Bn + row) * 16 + sl];
  float sssq = p1[(size_t)(1 * Bn + row) * 16 + sl];
  float smxn = p1[(size_t)(2 * Bn + row) * 16 + sl];
  float smnp = p1[(size_t)(3 * Bn + row) * 16 + sl];
  float spc  = p1[(size_t)(4 * Bn + row) * 16 + sl];
#pragma unroll
  for (int d = 1; d < 16; d <<= 1) {
    ssum += __shfl_xor(ssum, d);
    sssq += __shfl_xor(sssq, d);
    smxn = fmaxf(smxn, __shfl_xor(smxn, d));
    smnp = fminf(smnp, __shfl_xor(smnp, d));
    spc += __shfl_xor(spc, d);
  }
  const float thrp = smxn;  // max_neg
  const float thrn = smnp;  // min_pos

  float np = 0.f, nn = 0.f, ssel = 0.f, qsel = 0.f, fp = 0.f, fn = 0.f;
  const unsigned short* rp = simb + (size_t)row * Bn;
#pragma unroll
  for (int it = 0; it < 8; ++it) {
    const int base = it * 512 + lane * 8;
    bf16x8 v = *(const bf16x8*)(rp + base);
    int4 la = *(const int4*)&labels[base];
    int4 lb = *(const int4*)&labels[base + 4];
    int lv[8] = {la.x, la.y, la.z, la.w, lb.x, lb.y, lb.z, lb.w};
#pragma unroll
    for (int e = 0; e < 8; ++e) {
      float s = __uint_as_float(((unsigned int)(unsigned short)v[e]) << 16);
      bool same = (lv[e] == rlab);
      bool psel = same && (s < ONE_EPS) && (s - 0.1f < thrp);
      bool nsel = (!same) && (s + 0.1f > thrn);
      if (psel) { np += 1.f; fp += __expf(2.0f - 2.0f * s); }
      if (nsel) { nn += 1.f; fn += __expf(2.0f * s - 1.2f); }
      if (psel || nsel) { ssel += s; qsel += s * s; }
    }
  }
#pragma unroll
  for (int d = 1; d < 64; d <<= 1) {
    np += __shfl_xor(np, d); nn += __shfl_xor(nn, d);
    ssel += __shfl_xor(ssel, d); qsel += __shfl_xor(qsel, d);
    fp += __shfl_xor(fp, d); fn += __shfl_xor(fn, d);
  }
  if (lane == 0) {
    float mean_all = ssum * (1.0f / Bn);
    float sigma_all = sssq - (float)Bn * mean_all * mean_all;
    float cnt = fmaxf(np + nn, 1.0f);
    float mean_sel = ssel / cnt;
    float sigma_sel = qsel / cnt - mean_sel * mean_sel;
    float loss = __logf(1.0f + fp) + __logf(1.0f + fn) +
                 0.5f * (fabsf(mean_all - mean_sel) + fabsf(sigma_all - sigma_sel));
    bool valid = (spc > 0.5f) && (spc < (float)(Bn - 1) - 0.5f) && (np > 0.5f) && (nn > 0.5f);
    bres[row] = valid ? loss : 0.f;
  }
}

// ---- Path A final: sum 4096 per-row losses -> out (single block, no atomics) ----
__global__ __launch_bounds__(256) void sum_kernel(const float* __restrict__ bres,
                                                  float* __restrict__ out) {
  const int tid = threadIdx.x;
  float v = 0.f;
#pragma unroll
  for (int i = 0; i < 16; ++i) v += bres[i * 256 + tid];
#pragma unroll
  for (int d = 1; d < 64; d <<= 1) v += __shfl_xor(v, d);
  __shared__ float ls[4];
  if ((tid & 63) == 0) ls[tid >> 6] = v;
  __syncthreads();
  if (tid == 0) out[0] = (ls[0] + ls[1] + ls[2] + ls[3]) * (1.0f / (float)Bn);
}

// ---- Path B (fallback) helpers ----
__global__ __launch_bounds__(256) void reduce1_kernel(const float* __restrict__ part,
                                                      float* __restrict__ rs) {
  int row = blockIdx.x * 256 + threadIdx.x;
  float sum = 0.f, ssq = 0.f, pc = 0.f;
  float mxn = -__builtin_inff(), mnp = __builtin_inff();
#pragma unroll
  for (int sl = 0; sl < 16; ++sl) {
    sum += part[(size_t)(0 * Bn + row) * 16 + sl];
    ssq += part[(size_t)(1 * Bn + row) * 16 + sl];
    mxn = fmaxf(mxn, part[(size_t)(2 * Bn + row) * 16 + sl]);
    mnp = fminf(mnp, part[(size_t)(3 * Bn + row) * 16 + sl]);
    pc += part[(size_t)(4 * Bn + row) * 16 + sl];
  }
  rs[0 * Bn + row] = sum;
  rs[1 * Bn + row] = ssq;
  rs[2 * Bn + row] = mxn;
  rs[3 * Bn + row] = mnp;
  rs[4 * Bn + row] = pc;
}

__global__ __launch_bounds__(256) void finalize_kernel(const float* __restrict__ p2,
                                                       const float* __restrict__ rs,
                                                       float* __restrict__ out) {
  int tid = threadIdx.x;
  int row = blockIdx.x * 256 + tid;
  float np = 0.f, nn = 0.f, ssel = 0.f, qsel = 0.f, fp = 0.f, fn = 0.f;
#pragma unroll
  for (int sl = 0; sl < 16; ++sl) {
    np += p2[(size_t)(0 * Bn + row) * 16 + sl];
    nn += p2[(size_t)(1 * Bn + row) * 16 + sl];
    ssel += p2[(size_t)(2 * Bn + row) * 16 + sl];
    qsel += p2[(size_t)(3 * Bn + row) * 16 + sl];
    fp += p2[(size_t)(4 * Bn + row) * 16 + sl];
    fn += p2[(size_t)(5 * Bn + row) * 16 + sl];
  }
  float sumall = rs[0 * Bn + row];
  float ssqall = rs[1 * Bn + row];
  float pc = rs[4 * Bn + row];

  float mean_all = sumall * (1.0f / Bn);
  float sigma_all = ssqall - (float)Bn * mean_all * mean_all;
  float cnt = fmaxf(np + nn, 1.0f);
  float mean_sel = ssel / cnt;
  float sigma_sel = qsel / cnt - mean_sel * mean_sel;
  float loss = __logf(1.0f + fp) + __logf(1.0f + fn) +
               0.5f * (fabsf(mean_all - mean_sel) + fabsf(sigma_all - sigma_sel));
  bool valid = (pc > 0.5f) && (pc < (float)(Bn - 1) - 0.5f) && (np > 0.5f) && (nn > 0.5f);
  float v = valid ? loss : 0.f;
#pragma unroll
  for (int d = 1; d < 64; d <<= 1) v += __shfl_xor(v, d);
  __shared__ float ls[4];
  if ((tid & 63) == 0) ls[tid >> 6] = v;
  __syncthreads();
  if (tid == 0) atomicAdd(out, (ls[0] + ls[1] + ls[2] + ls[3]) * (1.0f / (float)Bn));
}

extern "C" void kernel_launch(void* const* d_in, const int* in_sizes, int n_in,
                              void* d_out, int out_size, void* d_ws, size_t ws_size,
                              hipStream_t stream) {
  const float* feats = (const float*)d_in[0];
  const int* labels = (const int*)d_in[1];
  float* out = (float*)d_out;
  char* ws = (char*)d_ws;

  unsigned short* featT = (unsigned short*)ws;                      // 4,194,304
  float* p1 = (float*)(ws + 4194304);                               // 5*4096*16*4 = 1,310,720
  const size_t needA = 4194304ull + 1310720ull + 33554432ull + 16384ull;  // + simb + bres

  convert_kernel<<<512, 256, 0, stream>>>(feats, featT);
  dim3 g(Bn / BM, NCHUNK);

  if (ws_size >= needA) {
    // Path A: single GEMM with sim materialization, streaming pass 2, no atomics.
    unsigned short* simb = (unsigned short*)(ws + 4194304 + 1310720);
    float* bres = (float*)(ws + 4194304 + 1310720 + 33554432);
    phase_kernel<1, true><<<g, 512, 0, stream>>>(featT, labels, nullptr, p1, simb);
    pass2_kernel<<<Bn, 64, 0, stream>>>(simb, labels, p1, bres);
    sum_kernel<<<1, 256, 0, stream>>>(bres, out);
  } else {
    // Path B: two-GEMM structure.
    float* rs = (float*)(ws + 4194304 + 1310720);                   // 81,920
    float* p2 = (float*)(ws + 4194304 + 1310720 + 81920);           // 1,572,864
    hipMemsetAsync(d_out, 0, sizeof(float), stream);
    phase_kernel<1, false><<<g, 512, 0, stream>>>(featT, labels, nullptr, p1, nullptr);
    reduce1_kernel<<<Bn / 256, 256, 0, stream>>>(p1, rs);
    phase_kernel<2, false><<<g, 512, 0, stream>>>(featT, labels, rs, p2, nullptr);
    finalize_kernel<<<Bn / 256, 256, 0, stream>>>(p2, rs, out);
  }
}